// Round 8
// baseline (459.006 us; speedup 1.0000x reference)
//
#include <hip/hip_runtime.h>

#define N_USERS 100000
#define N_ITEMS 50000
#define N_NODES 150000
#define N_EDGES 2400000
#define EMB 64
#define LEAKY 0.3f

#define SCAN_CHUNK 1024
#define NBLK ((N_NODES + SCAN_CHUNK - 1) / SCAN_CHUNK)    // 147

#define RB_SHIFT 8                                         // 256 rows / bucket
#define RB (1 << RB_SHIFT)
#define NBKT ((N_NODES + RB - 1) >> RB_SHIFT)              // 586
#define L1_CHUNK 8192
#define NBLK_L1 ((N_EDGES + L1_CHUNK - 1) / L1_CHUNK)      // 293
#define COL_MASK 0x3FFFFu                                  // col < 2^18

typedef unsigned short u16;
typedef unsigned int   u32;

__device__ __forceinline__ u16 f32_to_bf16_rne(float f) {
    u32 u = __float_as_uint(f);
    u32 r = (u + 0x7FFFu + ((u >> 16) & 1u)) >> 16;
    return (u16)r;
}
__device__ __forceinline__ float bf16_lo(u32 x) { return __uint_as_float(x << 16); }
__device__ __forceinline__ float bf16_hi(u32 x) { return __uint_as_float(x & 0xFFFF0000u); }

// ===========================================================================
// e0 -> bf16 (concatenated user ++ item), RNE
// ===========================================================================
__global__ __launch_bounds__(256) void conv_e0(
    const float* __restrict__ uemb, const float* __restrict__ iemb,
    u16* __restrict__ ebf)
{
    const int i = (blockIdx.x * 256 + threadIdx.x) * 4;
    if (i >= N_NODES * EMB) return;
    const float* src = (i < N_USERS * EMB) ? uemb + i : iemb + (i - N_USERS * EMB);
    const float4 v = *(const float4*)src;
    ushort4 w;
    w.x = f32_to_bf16_rne(v.x);
    w.y = f32_to_bf16_rne(v.y);
    w.z = f32_to_bf16_rne(v.z);
    w.w = f32_to_bf16_rne(v.w);
    *(ushort4*)(ebf + i) = w;
}

// ===========================================================================
// CSR build: row histogram -> hierarchical exclusive scan (round-2 proven)
// ===========================================================================
__global__ __launch_bounds__(256) void hist_kernel(
    const int* __restrict__ rows, int* __restrict__ cnt)
{
    const int i = blockIdx.x * 256 + threadIdx.x;
    if (i < N_EDGES) atomicAdd(&cnt[rows[i]], 1);
}

__global__ __launch_bounds__(256) void scan_partial(
    const int* __restrict__ cnt, int* __restrict__ blk_sums)
{
    __shared__ int lds[256];
    const int b = blockIdx.x, t = threadIdx.x;
    const int base = b * SCAN_CHUNK + t * 4;
    int s = 0;
    #pragma unroll
    for (int j = 0; j < 4; ++j) {
        const int idx = base + j;
        if (idx < N_NODES) s += cnt[idx];
    }
    lds[t] = s;
    __syncthreads();
    for (int off = 128; off > 0; off >>= 1) {
        if (t < off) lds[t] += lds[t + off];
        __syncthreads();
    }
    if (t == 0) blk_sums[b] = lds[0];
}

__global__ __launch_bounds__(256) void scan_blk(
    const int* __restrict__ blk_sums, int* __restrict__ blk_offs)
{
    __shared__ int lds[256];
    const int t = threadIdx.x;
    const int v = (t < NBLK) ? blk_sums[t] : 0;
    lds[t] = v;
    __syncthreads();
    for (int off = 1; off < 256; off <<= 1) {
        int x = 0;
        if (t >= off) x = lds[t - off];
        __syncthreads();
        lds[t] += x;
        __syncthreads();
    }
    if (t < NBLK) blk_offs[t] = lds[t] - v;
}

__global__ __launch_bounds__(256) void scan_apply(
    const int* __restrict__ cnt, const int* __restrict__ blk_offs,
    int* __restrict__ row_ptr)
{
    __shared__ int lds[256];
    const int b = blockIdx.x, t = threadIdx.x;
    const int base = b * SCAN_CHUNK + t * 4;
    int v[4];
    int s = 0;
    #pragma unroll
    for (int j = 0; j < 4; ++j) {
        const int idx = base + j;
        v[j] = (idx < N_NODES) ? cnt[idx] : 0;
        s += v[j];
    }
    lds[t] = s;
    __syncthreads();
    for (int off = 1; off < 256; off <<= 1) {
        int x = 0;
        if (t >= off) x = lds[t - off];
        __syncthreads();
        lds[t] += x;
        __syncthreads();
    }
    int run = blk_offs[b] + (lds[t] - s);
    #pragma unroll
    for (int j = 0; j < 4; ++j) {
        const int idx = base + j;
        if (idx < N_NODES) {
            row_ptr[idx] = run;
            run += v[j];
        }
    }
}

__global__ __launch_bounds__(256) void init_aux(
    int* __restrict__ row_ptr, int* __restrict__ bkt_tail)
{
    const int i = blockIdx.x * 256 + threadIdx.x;
    if (i == 0) row_ptr[N_NODES] = N_EDGES;
    if (i < NBKT) bkt_tail[i] = row_ptr[(size_t)i << RB_SHIFT];
}

// ===========================================================================
// Two-level edge sort (round-3 proven; localrow packed into the col word)
// ===========================================================================
__global__ __launch_bounds__(256) void partition_l1(
    const float* __restrict__ vals, const int* __restrict__ rows,
    const int* __restrict__ cols, int* __restrict__ bkt_tail,
    float2* __restrict__ svc)
{
    __shared__ int cnt[NBKT];
    __shared__ int base[NBKT];
    const int t = threadIdx.x;
    const int e0 = blockIdx.x * L1_CHUNK;
    const int e1 = (e0 + L1_CHUNK < N_EDGES) ? e0 + L1_CHUNK : N_EDGES;

    for (int b = t; b < NBKT; b += 256) cnt[b] = 0;
    __syncthreads();

    for (int i = e0 + t; i < e1; i += 256)
        atomicAdd(&cnt[rows[i] >> RB_SHIFT], 1);
    __syncthreads();

    for (int b = t; b < NBKT; b += 256) {
        const int c = cnt[b];
        base[b] = c ? atomicAdd(&bkt_tail[b], c) : 0;
        cnt[b] = 0;
    }
    __syncthreads();

    for (int i = e0 + t; i < e1; i += 256) {
        const int r = rows[i];
        const int b = r >> RB_SHIFT;
        const int pos = base[b] + atomicAdd(&cnt[b], 1);
        const u32 packed = ((u32)(r & (RB - 1)) << 18) | (u32)cols[i];
        svc[pos] = make_float2(vals[i], __uint_as_float(packed));
    }
}

__global__ __launch_bounds__(256) void place_l2(
    const int* __restrict__ row_ptr, const float2* __restrict__ svc,
    float2* __restrict__ sedge)
{
    __shared__ int h[RB];
    const int b     = blockIdx.x;
    const int rbase = b << RB_SHIFT;
    const int t     = threadIdx.x;

    h[t] = (rbase + t < N_NODES) ? row_ptr[rbase + t] : 0;
    __syncthreads();

    const int lo = row_ptr[rbase];
    int hidx = rbase + RB;
    if (hidx > N_NODES) hidx = N_NODES;
    const int hi = row_ptr[hidx];

    for (int i = lo + t; i < hi; i += 256) {
        const float2 vc = svc[i];
        const int lr   = (int)(__float_as_uint(vc.y) >> 18);
        const int pos  = atomicAdd(&h[lr], 1);
        sedge[pos] = vc;
    }
}

// ===========================================================================
// Pull-SpMM over bf16 source: one 64-lane wave per row; lane = (edge-half,
// feature-pair). Each gather dword covers 2 bf16 features of one edge; the
// wave gathers 2 edges per VMEM instruction. 8 edges in flight per iter.
// ===========================================================================
__global__ __launch_bounds__(256) void spmm_bf16(
    const int* __restrict__ row_ptr,     // N_NODES+1
    const float2* __restrict__ sedge,    // (val, packed) row-sorted
    const u16* __restrict__ ebf,         // [N_NODES][64] bf16
    float* __restrict__ t_out)           // [N_NODES][64] f32
{
    const int tid  = threadIdx.x;
    const int lane = tid & 63;
    const int row  = blockIdx.x * 4 + (tid >> 6);
    if (row >= N_NODES) return;

    const int h = lane >> 5;    // edge half: 0 or 1
    const int q = lane & 31;    // feature pair: features 2q, 2q+1

    const int beg = row_ptr[row];
    const int end = row_ptr[row + 1];

    float a0 = 0.f, a1 = 0.f, b0 = 0.f, b1 = 0.f;
    float c0 = 0.f, c1 = 0.f, d0 = 0.f, d1 = 0.f;

    int k = beg;
    for (; k + 8 <= end; k += 8) {
        const float2 m0 = sedge[k + 0 + h];
        const float2 m1 = sedge[k + 2 + h];
        const float2 m2 = sedge[k + 4 + h];
        const float2 m3 = sedge[k + 6 + h];
        const u32 i0 = __float_as_uint(m0.y) & COL_MASK;
        const u32 i1 = __float_as_uint(m1.y) & COL_MASK;
        const u32 i2 = __float_as_uint(m2.y) & COL_MASK;
        const u32 i3 = __float_as_uint(m3.y) & COL_MASK;
        const u32 x0 = *((const u32*)(ebf + (size_t)i0 * EMB) + q);
        const u32 x1 = *((const u32*)(ebf + (size_t)i1 * EMB) + q);
        const u32 x2 = *((const u32*)(ebf + (size_t)i2 * EMB) + q);
        const u32 x3 = *((const u32*)(ebf + (size_t)i3 * EMB) + q);
        a0 = fmaf(m0.x, bf16_lo(x0), a0);
        a1 = fmaf(m0.x, bf16_hi(x0), a1);
        b0 = fmaf(m1.x, bf16_lo(x1), b0);
        b1 = fmaf(m1.x, bf16_hi(x1), b1);
        c0 = fmaf(m2.x, bf16_lo(x2), c0);
        c1 = fmaf(m2.x, bf16_hi(x2), c1);
        d0 = fmaf(m3.x, bf16_lo(x3), d0);
        d1 = fmaf(m3.x, bf16_hi(x3), d1);
    }
    // tail (0..7 edges), processed 2 at a time with clamped index / zero val
    for (; k < end; k += 2) {
        const int  kk = k + h;
        const bool on = kk < end;
        const float2 m = sedge[on ? kk : (end - 1)];
        const float  v = on ? m.x : 0.f;
        const u32 ci = __float_as_uint(m.y) & COL_MASK;
        const u32 x  = *((const u32*)(ebf + (size_t)ci * EMB) + q);
        a0 = fmaf(v, bf16_lo(x), a0);
        a1 = fmaf(v, bf16_hi(x), a1);
    }

    float s0 = (a0 + b0) + (c0 + d0);
    float s1 = (a1 + b1) + (c1 + d1);
    s0 += __shfl_xor(s0, 32);
    s1 += __shfl_xor(s1, 32);

    if (h == 0)
        *(float2*)(t_out + (size_t)row * EMB + 2 * q) = make_float2(s0, s1);
}

// ===========================================================================
// Dense stage: e_out = t @ W^T fused with LeakyReLU + 0.25-mean accumulation.
// FIRST also emits e2 as bf16 (stage-2 gather source).
// ===========================================================================
template <bool FIRST>
__global__ __launch_bounds__(256) void dense_stage(
    const float* __restrict__ t, const float* __restrict__ W,
    const float* __restrict__ user_emb, const float* __restrict__ item_emb,
    u16* __restrict__ e2bf, float* __restrict__ out)
{
    __shared__ float wT[64][65];
    __shared__ float trow[16][64];

    const int tid = threadIdx.x;
    for (int k = tid; k < 64 * 64; k += 256) {
        const int i = k >> 6, j = k & 63;
        wT[j][i] = W[k];
    }
    const int row_base = blockIdx.x * 16;
    for (int k = tid; k < 16 * 64; k += 256) {
        const int r = k >> 6, j = k & 63;
        const int row = row_base + r;
        trow[r][j] = (row < N_NODES) ? t[(size_t)row * EMB + j] : 0.f;
    }
    __syncthreads();

    const int i  = tid & 63;
    const int r0 = tid >> 6;

    #pragma unroll
    for (int rr = 0; rr < 4; ++rr) {
        const int r   = r0 * 4 + rr;
        const int row = row_base + r;
        if (row >= N_NODES) continue;

        float acc = 0.f;
        #pragma unroll
        for (int j = 0; j < 64; ++j)
            acc = fmaf(trow[r][j], wT[j][i], acc);

        const size_t idx = (size_t)row * EMB + i;
        if (FIRST) {
            const float e1v = acc;
            const float e2v = (e1v >= 0.f) ? e1v : LEAKY * e1v;
            const float e0v = (row < N_USERS)
                                  ? user_emb[idx]
                                  : item_emb[(size_t)(row - N_USERS) * EMB + i];
            e2bf[idx] = f32_to_bf16_rne(e2v);
            out[idx]  = 0.25f * (e0v + e1v + e2v);
        } else {
            out[idx] += 0.25f * acc;
        }
    }
}

// ===========================================================================
// Fallback (round-1 proven): atomic SpMM + f32 dense, if ws too small.
// ===========================================================================
__global__ __launch_bounds__(256) void spmm_atomic(
    const float* __restrict__ vals, const int* __restrict__ rows,
    const int* __restrict__ cols, const float* __restrict__ src_a,
    const float* __restrict__ src_b, float* __restrict__ dst)
{
    const int tid  = threadIdx.x;
    const int lane = tid & 63;
    const int e    = blockIdx.x * 4 + (tid >> 6);
    if (e >= N_EDGES) return;
    const float v = vals[e];
    const int   c = cols[e];
    const int   r = rows[e];
    const float* src = (src_b != nullptr && c >= N_USERS)
                           ? src_b + (size_t)(c - N_USERS) * EMB
                           : src_a + (size_t)c * EMB;
    unsafeAtomicAdd(&dst[(size_t)r * EMB + lane], v * src[lane]);
}

template <bool FIRST>
__global__ __launch_bounds__(256) void dense_f32(
    const float* __restrict__ t, const float* __restrict__ W,
    const float* __restrict__ user_emb, const float* __restrict__ item_emb,
    float* __restrict__ e2, float* __restrict__ out)
{
    __shared__ float wT[64][65];
    __shared__ float trow[16][64];

    const int tid = threadIdx.x;
    for (int k = tid; k < 64 * 64; k += 256) {
        const int i = k >> 6, j = k & 63;
        wT[j][i] = W[k];
    }
    const int row_base = blockIdx.x * 16;
    for (int k = tid; k < 16 * 64; k += 256) {
        const int r = k >> 6, j = k & 63;
        const int row = row_base + r;
        trow[r][j] = (row < N_NODES) ? t[(size_t)row * EMB + j] : 0.f;
    }
    __syncthreads();

    const int i  = tid & 63;
    const int r0 = tid >> 6;

    #pragma unroll
    for (int rr = 0; rr < 4; ++rr) {
        const int r   = r0 * 4 + rr;
        const int row = row_base + r;
        if (row >= N_NODES) continue;
        float acc = 0.f;
        #pragma unroll
        for (int j = 0; j < 64; ++j)
            acc = fmaf(trow[r][j], wT[j][i], acc);
        const size_t idx = (size_t)row * EMB + i;
        if (FIRST) {
            const float e1v = acc;
            const float e2v = (e1v >= 0.f) ? e1v : LEAKY * e1v;
            const float e0v = (row < N_USERS)
                                  ? user_emb[idx]
                                  : item_emb[(size_t)(row - N_USERS) * EMB + i];
            e2[idx]  = e2v;
            out[idx] = 0.25f * (e0v + e1v + e2v);
        } else {
            out[idx] += 0.25f * acc;
        }
    }
}

// ===========================================================================
extern "C" void kernel_launch(void* const* d_in, const int* in_sizes, int n_in,
                              void* d_out, int out_size, void* d_ws, size_t ws_size,
                              hipStream_t stream)
{
    const float* user_emb = (const float*)d_in[0];
    const float* item_emb = (const float*)d_in[1];
    const float* W0       = (const float*)d_in[2];
    const float* W1       = (const float*)d_in[3];
    const float* adj_vals = (const float*)d_in[4];
    const int*   adj_rows = (const int*)d_in[5];
    const int*   adj_cols = (const int*)d_in[6];
    float*       out      = (float*)d_out;

    const size_t mat_bytes = (size_t)N_NODES * EMB * sizeof(float);   // 38.4 MB
    const size_t ebf_bytes = (size_t)N_NODES * EMB * sizeof(u16);     // 19.2 MB
    const size_t edge8     = (size_t)N_EDGES * sizeof(float2);        // 19.2 MB
    const size_t node_ints = (size_t)N_NODES * sizeof(int);

    // layout: [t 38.4 | svc transient in first 19.2] [sedge 19.2] [ebf 19.2
    // shared e0/e2] [aux]
    const size_t off_t      = 0;
    const size_t off_svc    = 0;                       // transient, inside t
    const size_t off_sedge  = off_t + mat_bytes;
    const size_t off_ebf    = off_sedge + edge8;
    const size_t off_cnt    = off_ebf + ebf_bytes;
    const size_t off_rowptr = off_cnt + node_ints;
    const size_t off_tails  = off_rowptr + (size_t)(N_NODES + 1) * sizeof(int);
    const size_t off_bsums  = off_tails + ((NBKT + 255) & ~255) * sizeof(int);
    const size_t off_boffs  = off_bsums + 1024;
    const size_t required   = off_boffs + 1024;        // ~78.8 MB

    const int edge_blocks  = (N_EDGES + 255) / 256;
    const int dense_blocks = (N_NODES + 15) / 16;      // 9375
    const int spmm_blocks  = (N_NODES + 3) / 4;        // 37500
    const int conv_blocks  = (N_NODES * EMB / 4 + 255) / 256;

    if (ws_size >= required) {
        float*  t       = (float*)((char*)d_ws + off_t);
        float2* svc     = (float2*)((char*)d_ws + off_svc);
        float2* sedge   = (float2*)((char*)d_ws + off_sedge);
        u16*    ebf     = (u16*)((char*)d_ws + off_ebf);
        int*    cnt     = (int*)((char*)d_ws + off_cnt);
        int*    row_ptr = (int*)((char*)d_ws + off_rowptr);
        int*    tails   = (int*)((char*)d_ws + off_tails);
        int*    bsums   = (int*)((char*)d_ws + off_bsums);
        int*    boffs   = (int*)((char*)d_ws + off_boffs);

        // ---- bf16 source for stage 1 ----
        conv_e0<<<conv_blocks, 256, 0, stream>>>(user_emb, item_emb, ebf);

        // ---- CSR build (once, reused twice) ----
        hipMemsetAsync(cnt, 0, node_ints, stream);
        hist_kernel<<<edge_blocks, 256, 0, stream>>>(adj_rows, cnt);
        scan_partial<<<NBLK, 256, 0, stream>>>(cnt, bsums);
        scan_blk<<<1, 256, 0, stream>>>(bsums, boffs);
        scan_apply<<<NBLK, 256, 0, stream>>>(cnt, boffs, row_ptr);
        init_aux<<<(NBKT + 255) / 256, 256, 0, stream>>>(row_ptr, tails);
        partition_l1<<<NBLK_L1, 256, 0, stream>>>(
            adj_vals, adj_rows, adj_cols, tails, svc);
        place_l2<<<NBKT, RB, 0, stream>>>(row_ptr, svc, sedge);
        // svc (inside t) is dead from here on

        // ---- stage 1: t = A @ e0 ; e1/e2/out ; e2 -> ebf (bf16) ----
        spmm_bf16<<<spmm_blocks, 256, 0, stream>>>(row_ptr, sedge, ebf, t);
        dense_stage<true><<<dense_blocks, 256, 0, stream>>>(
            t, W0, user_emb, item_emb, ebf, out);

        // ---- stage 2: t = A @ e2 ; out += 0.25*e3 ----
        spmm_bf16<<<spmm_blocks, 256, 0, stream>>>(row_ptr, sedge, ebf, t);
        dense_stage<false><<<dense_blocks, 256, 0, stream>>>(
            t, W1, nullptr, nullptr, nullptr, out);
    } else {
        // ---- fallback: round-1 atomic path ----
        float* t  = (float*)d_ws;
        float* e2 = (float*)((char*)d_ws + mat_bytes);

        hipMemsetAsync(t, 0, mat_bytes, stream);
        spmm_atomic<<<(N_EDGES + 3) / 4, 256, 0, stream>>>(
            adj_vals, adj_rows, adj_cols, user_emb, item_emb, t);
        dense_f32<true><<<dense_blocks, 256, 0, stream>>>(
            t, W0, user_emb, item_emb, e2, out);

        hipMemsetAsync(t, 0, mat_bytes, stream);
        spmm_atomic<<<(N_EDGES + 3) / 4, 256, 0, stream>>>(
            adj_vals, adj_rows, adj_cols, e2, nullptr, t);
        dense_f32<false><<<dense_blocks, 256, 0, stream>>>(
            t, W1, nullptr, nullptr, nullptr, out);
    }
}

// Round 9
// 391.078 us; speedup vs baseline: 1.1737x; 1.1737x over previous
//
#include <hip/hip_runtime.h>

#define N_USERS 100000
#define N_ITEMS 50000
#define N_NODES 150000
#define N_EDGES 2400000
#define EMB 64
#define LEAKY 0.3f

#define RB_SHIFT 8                                         // 256 rows / bucket
#define RB (1 << RB_SHIFT)
#define NBKT ((N_NODES + RB - 1) >> RB_SHIFT)              // 586
#define SCAN_ITEMS ((NBKT + 255) / 256)                    // 3
#define L1_CHUNK 16384
#define NBLK_L1 ((N_EDGES + L1_CHUNK - 1) / L1_CHUNK)      // 147
#define COL_MASK 0x3FFFFu                                  // col < 2^18

typedef unsigned short u16;
typedef unsigned int   u32;

__device__ __forceinline__ u16 f32_to_bf16_rne(float f) {
    u32 u = __float_as_uint(f);
    u32 r = (u + 0x7FFFu + ((u >> 16) & 1u)) >> 16;
    return (u16)r;
}
__device__ __forceinline__ float bf16_lo(u32 x) { return __uint_as_float(x << 16); }
__device__ __forceinline__ float bf16_hi(u32 x) { return __uint_as_float(x & 0xFFFF0000u); }

// ===========================================================================
// e0 -> bf16 (concatenated user ++ item), RNE
// ===========================================================================
__global__ __launch_bounds__(256) void conv_e0(
    const float* __restrict__ uemb, const float* __restrict__ iemb,
    u16* __restrict__ ebf)
{
    const int i = (blockIdx.x * 256 + threadIdx.x) * 4;
    if (i >= N_NODES * EMB) return;
    const float* src = (i < N_USERS * EMB) ? uemb + i : iemb + (i - N_USERS * EMB);
    const float4 v = *(const float4*)src;
    ushort4 w;
    w.x = f32_to_bf16_rne(v.x);
    w.y = f32_to_bf16_rne(v.y);
    w.z = f32_to_bf16_rne(v.z);
    w.w = f32_to_bf16_rne(v.w);
    *(ushort4*)(ebf + i) = w;
}

// ===========================================================================
// Bucket histogram (LDS-aggregated, 586 counters — no per-row hist anymore)
// ===========================================================================
__global__ __launch_bounds__(256) void bkt_hist(
    const int* __restrict__ rows, int* __restrict__ gcnt)
{
    __shared__ int cnt[NBKT];
    const int t = threadIdx.x;
    for (int b = t; b < NBKT; b += 256) cnt[b] = 0;
    __syncthreads();

    const int e0 = blockIdx.x * L1_CHUNK;
    const int e1 = (e0 + L1_CHUNK < N_EDGES) ? e0 + L1_CHUNK : N_EDGES;
    for (int i = e0 + t; i < e1; i += 256)
        atomicAdd(&cnt[rows[i] >> RB_SHIFT], 1);
    __syncthreads();

    for (int b = t; b < NBKT; b += 256)
        if (cnt[b]) atomicAdd(&gcnt[b], cnt[b]);
}

// ===========================================================================
// Exclusive scan of the NBKT bucket counts (single block)
// ===========================================================================
__global__ __launch_bounds__(256) void scan_bkt(
    const int* __restrict__ gcnt, int* __restrict__ bkt_ptr,
    int* __restrict__ bkt_tail)
{
    __shared__ int lds[256];
    const int t = threadIdx.x;
    int v[SCAN_ITEMS];
    int s = 0;
    #pragma unroll
    for (int j = 0; j < SCAN_ITEMS; ++j) {
        const int idx = t * SCAN_ITEMS + j;
        v[j] = (idx < NBKT) ? gcnt[idx] : 0;
        s += v[j];
    }
    lds[t] = s;
    __syncthreads();
    for (int off = 1; off < 256; off <<= 1) {
        int x = 0;
        if (t >= off) x = lds[t - off];
        __syncthreads();
        lds[t] += x;
        __syncthreads();
    }
    int run = lds[t] - s;   // exclusive prefix
    #pragma unroll
    for (int j = 0; j < SCAN_ITEMS; ++j) {
        const int idx = t * SCAN_ITEMS + j;
        if (idx < NBKT) {
            bkt_ptr[idx]  = run;
            bkt_tail[idx] = run;
            run += v[j];
        }
    }
    if (t == 255) bkt_ptr[NBKT] = N_EDGES;
}

// ===========================================================================
// Partition: bin edges into 256-row buckets; record = (val, (localrow<<18)|col)
// ===========================================================================
__global__ __launch_bounds__(256) void partition_l1(
    const float* __restrict__ vals, const int* __restrict__ rows,
    const int* __restrict__ cols, int* __restrict__ bkt_tail,
    float2* __restrict__ svc)
{
    __shared__ int cnt[NBKT];
    __shared__ int base[NBKT];
    const int t = threadIdx.x;
    const int e0 = blockIdx.x * L1_CHUNK;
    const int e1 = (e0 + L1_CHUNK < N_EDGES) ? e0 + L1_CHUNK : N_EDGES;

    for (int b = t; b < NBKT; b += 256) cnt[b] = 0;
    __syncthreads();

    for (int i = e0 + t; i < e1; i += 256)
        atomicAdd(&cnt[rows[i] >> RB_SHIFT], 1);
    __syncthreads();

    for (int b = t; b < NBKT; b += 256) {
        const int c = cnt[b];
        base[b] = c ? atomicAdd(&bkt_tail[b], c) : 0;
        cnt[b] = 0;
    }
    __syncthreads();

    for (int i = e0 + t; i < e1; i += 256) {
        const int r = rows[i];
        const int b = r >> RB_SHIFT;
        const int pos = base[b] + atomicAdd(&cnt[b], 1);
        const u32 packed = ((u32)(r & (RB - 1)) << 18) | (u32)cols[i];
        svc[pos] = make_float2(vals[i], __uint_as_float(packed));
    }
}

// ===========================================================================
// place_l2 (merged): per-row count (LDS) -> LDS scan -> row_ptr write ->
// in-bucket placement via LDS heads. Replaces hist+scan_partial+scan_blk+
// scan_apply+init_aux and the old place_l2.
// ===========================================================================
__global__ __launch_bounds__(256) void place_l2(
    const int* __restrict__ bkt_ptr, const float2* __restrict__ svc,
    float2* __restrict__ sedge, int* __restrict__ row_ptr)
{
    __shared__ int cnt[RB];     // reused as scan array
    __shared__ int heads[RB];
    const int b     = blockIdx.x;
    const int rbase = b << RB_SHIFT;
    const int t     = threadIdx.x;

    cnt[t] = 0;
    __syncthreads();

    const int lo = bkt_ptr[b];
    const int hi = bkt_ptr[b + 1];

    // phase A: per-local-row counts
    for (int i = lo + t; i < hi; i += 256)
        atomicAdd(&cnt[__float_as_uint(svc[i].y) >> 18], 1);
    __syncthreads();

    // phase B: exclusive scan over the 256 counters
    const int v = cnt[t];
    for (int off = 1; off < 256; off <<= 1) {
        int x = 0;
        if (t >= off) x = cnt[t - off];
        __syncthreads();
        cnt[t] += x;
        __syncthreads();
    }
    const int excl = cnt[t] - v;
    heads[t] = lo + excl;
    // row_ptr: every global row once; last bucket's t==240 writes the sentinel
    // row_ptr[N_NODES] = hi = N_EDGES (all counts past row N_NODES-1 are 0).
    const int gr = rbase + t;
    if (gr <= N_NODES) row_ptr[gr] = lo + excl;
    __syncthreads();

    // phase C: place edges (writes confined to one ~32KB range -> L2-local)
    for (int i = lo + t; i < hi; i += 256) {
        const float2 vc = svc[i];
        const int lr  = (int)(__float_as_uint(vc.y) >> 18);
        const int pos = atomicAdd(&heads[lr], 1);
        sedge[pos] = vc;
    }
}

// ===========================================================================
// Pull-SpMM over bf16 source: one 64-lane wave per row; lane = (edge-half,
// feature-pair). 8 edges in flight per iteration. (round-8 proven)
// ===========================================================================
__global__ __launch_bounds__(256) void spmm_bf16(
    const int* __restrict__ row_ptr,     // N_NODES+1
    const float2* __restrict__ sedge,    // (val, packed) row-sorted
    const u16* __restrict__ ebf,         // [N_NODES][64] bf16
    float* __restrict__ t_out)           // [N_NODES][64] f32
{
    const int tid  = threadIdx.x;
    const int lane = tid & 63;
    const int row  = blockIdx.x * 4 + (tid >> 6);
    if (row >= N_NODES) return;

    const int h = lane >> 5;    // edge half: 0 or 1
    const int q = lane & 31;    // feature pair: features 2q, 2q+1

    const int beg = row_ptr[row];
    const int end = row_ptr[row + 1];

    float a0 = 0.f, a1 = 0.f, b0 = 0.f, b1 = 0.f;
    float c0 = 0.f, c1 = 0.f, d0 = 0.f, d1 = 0.f;

    int k = beg;
    for (; k + 8 <= end; k += 8) {
        const float2 m0 = sedge[k + 0 + h];
        const float2 m1 = sedge[k + 2 + h];
        const float2 m2 = sedge[k + 4 + h];
        const float2 m3 = sedge[k + 6 + h];
        const u32 i0 = __float_as_uint(m0.y) & COL_MASK;
        const u32 i1 = __float_as_uint(m1.y) & COL_MASK;
        const u32 i2 = __float_as_uint(m2.y) & COL_MASK;
        const u32 i3 = __float_as_uint(m3.y) & COL_MASK;
        const u32 x0 = *((const u32*)(ebf + (size_t)i0 * EMB) + q);
        const u32 x1 = *((const u32*)(ebf + (size_t)i1 * EMB) + q);
        const u32 x2 = *((const u32*)(ebf + (size_t)i2 * EMB) + q);
        const u32 x3 = *((const u32*)(ebf + (size_t)i3 * EMB) + q);
        a0 = fmaf(m0.x, bf16_lo(x0), a0);
        a1 = fmaf(m0.x, bf16_hi(x0), a1);
        b0 = fmaf(m1.x, bf16_lo(x1), b0);
        b1 = fmaf(m1.x, bf16_hi(x1), b1);
        c0 = fmaf(m2.x, bf16_lo(x2), c0);
        c1 = fmaf(m2.x, bf16_hi(x2), c1);
        d0 = fmaf(m3.x, bf16_lo(x3), d0);
        d1 = fmaf(m3.x, bf16_hi(x3), d1);
    }
    for (; k < end; k += 2) {
        const int  kk = k + h;
        const bool on = kk < end;
        const float2 m = sedge[on ? kk : (end - 1)];
        const float  v = on ? m.x : 0.f;
        const u32 ci = __float_as_uint(m.y) & COL_MASK;
        const u32 x  = *((const u32*)(ebf + (size_t)ci * EMB) + q);
        a0 = fmaf(v, bf16_lo(x), a0);
        a1 = fmaf(v, bf16_hi(x), a1);
    }

    float s0 = (a0 + b0) + (c0 + d0);
    float s1 = (a1 + b1) + (c1 + d1);
    s0 += __shfl_xor(s0, 32);
    s1 += __shfl_xor(s1, 32);

    if (h == 0)
        *(float2*)(t_out + (size_t)row * EMB + 2 * q) = make_float2(s0, s1);
}

// ===========================================================================
// Dense stage: e_out = t @ W^T fused with LeakyReLU + 0.25-mean accumulation.
// FIRST also emits e2 as bf16 (stage-2 gather source). (round-8 proven)
// ===========================================================================
template <bool FIRST>
__global__ __launch_bounds__(256) void dense_stage(
    const float* __restrict__ t, const float* __restrict__ W,
    const float* __restrict__ user_emb, const float* __restrict__ item_emb,
    u16* __restrict__ e2bf, float* __restrict__ out)
{
    __shared__ float wT[64][65];
    __shared__ float trow[16][64];

    const int tid = threadIdx.x;
    for (int k = tid; k < 64 * 64; k += 256) {
        const int i = k >> 6, j = k & 63;
        wT[j][i] = W[k];
    }
    const int row_base = blockIdx.x * 16;
    for (int k = tid; k < 16 * 64; k += 256) {
        const int r = k >> 6, j = k & 63;
        const int row = row_base + r;
        trow[r][j] = (row < N_NODES) ? t[(size_t)row * EMB + j] : 0.f;
    }
    __syncthreads();

    const int i  = tid & 63;
    const int r0 = tid >> 6;

    #pragma unroll
    for (int rr = 0; rr < 4; ++rr) {
        const int r   = r0 * 4 + rr;
        const int row = row_base + r;
        if (row >= N_NODES) continue;

        float acc = 0.f;
        #pragma unroll
        for (int j = 0; j < 64; ++j)
            acc = fmaf(trow[r][j], wT[j][i], acc);

        const size_t idx = (size_t)row * EMB + i;
        if (FIRST) {
            const float e1v = acc;
            const float e2v = (e1v >= 0.f) ? e1v : LEAKY * e1v;
            const float e0v = (row < N_USERS)
                                  ? user_emb[idx]
                                  : item_emb[(size_t)(row - N_USERS) * EMB + i];
            e2bf[idx] = f32_to_bf16_rne(e2v);
            out[idx]  = 0.25f * (e0v + e1v + e2v);
        } else {
            out[idx] += 0.25f * acc;
        }
    }
}

// ===========================================================================
// Fallback (round-1 proven): atomic SpMM + f32 dense, if ws too small.
// ===========================================================================
__global__ __launch_bounds__(256) void spmm_atomic(
    const float* __restrict__ vals, const int* __restrict__ rows,
    const int* __restrict__ cols, const float* __restrict__ src_a,
    const float* __restrict__ src_b, float* __restrict__ dst)
{
    const int tid  = threadIdx.x;
    const int lane = tid & 63;
    const int e    = blockIdx.x * 4 + (tid >> 6);
    if (e >= N_EDGES) return;
    const float v = vals[e];
    const int   c = cols[e];
    const int   r = rows[e];
    const float* src = (src_b != nullptr && c >= N_USERS)
                           ? src_b + (size_t)(c - N_USERS) * EMB
                           : src_a + (size_t)c * EMB;
    unsafeAtomicAdd(&dst[(size_t)r * EMB + lane], v * src[lane]);
}

template <bool FIRST>
__global__ __launch_bounds__(256) void dense_f32(
    const float* __restrict__ t, const float* __restrict__ W,
    const float* __restrict__ user_emb, const float* __restrict__ item_emb,
    float* __restrict__ e2, float* __restrict__ out)
{
    __shared__ float wT[64][65];
    __shared__ float trow[16][64];

    const int tid = threadIdx.x;
    for (int k = tid; k < 64 * 64; k += 256) {
        const int i = k >> 6, j = k & 63;
        wT[j][i] = W[k];
    }
    const int row_base = blockIdx.x * 16;
    for (int k = tid; k < 16 * 64; k += 256) {
        const int r = k >> 6, j = k & 63;
        const int row = row_base + r;
        trow[r][j] = (row < N_NODES) ? t[(size_t)row * EMB + j] : 0.f;
    }
    __syncthreads();

    const int i  = tid & 63;
    const int r0 = tid >> 6;

    #pragma unroll
    for (int rr = 0; rr < 4; ++rr) {
        const int r   = r0 * 4 + rr;
        const int row = row_base + r;
        if (row >= N_NODES) continue;
        float acc = 0.f;
        #pragma unroll
        for (int j = 0; j < 64; ++j)
            acc = fmaf(trow[r][j], wT[j][i], acc);
        const size_t idx = (size_t)row * EMB + i;
        if (FIRST) {
            const float e1v = acc;
            const float e2v = (e1v >= 0.f) ? e1v : LEAKY * e1v;
            const float e0v = (row < N_USERS)
                                  ? user_emb[idx]
                                  : item_emb[(size_t)(row - N_USERS) * EMB + i];
            e2[idx]  = e2v;
            out[idx] = 0.25f * (e0v + e1v + e2v);
        } else {
            out[idx] += 0.25f * acc;
        }
    }
}

// ===========================================================================
extern "C" void kernel_launch(void* const* d_in, const int* in_sizes, int n_in,
                              void* d_out, int out_size, void* d_ws, size_t ws_size,
                              hipStream_t stream)
{
    const float* user_emb = (const float*)d_in[0];
    const float* item_emb = (const float*)d_in[1];
    const float* W0       = (const float*)d_in[2];
    const float* W1       = (const float*)d_in[3];
    const float* adj_vals = (const float*)d_in[4];
    const int*   adj_rows = (const int*)d_in[5];
    const int*   adj_cols = (const int*)d_in[6];
    float*       out      = (float*)d_out;

    const size_t mat_bytes = (size_t)N_NODES * EMB * sizeof(float);   // 38.4 MB
    const size_t ebf_bytes = (size_t)N_NODES * EMB * sizeof(u16);     // 19.2 MB
    const size_t edge8     = (size_t)N_EDGES * sizeof(float2);        // 19.2 MB

    // layout: [t 38.4 | svc transient inside t] [sedge 19.2] [ebf 19.2] [aux]
    const size_t off_t      = 0;
    const size_t off_svc    = 0;                       // transient, inside t
    const size_t off_sedge  = off_t + mat_bytes;
    const size_t off_ebf    = off_sedge + edge8;
    const size_t off_rowptr = off_ebf + ebf_bytes;
    const size_t off_gcnt   = off_rowptr + (size_t)(N_NODES + 1) * sizeof(int);
    const size_t off_ptr    = off_gcnt + (size_t)NBKT * sizeof(int);
    const size_t off_tails  = off_ptr + (size_t)(NBKT + 1) * sizeof(int);
    const size_t required   = off_tails + (size_t)NBKT * sizeof(int); // ~77.5 MB

    const int dense_blocks = (N_NODES + 15) / 16;      // 9375
    const int spmm_blocks  = (N_NODES + 3) / 4;        // 37500
    const int conv_blocks  = (N_NODES * EMB / 4 + 255) / 256;

    if (ws_size >= required) {
        float*  t        = (float*)((char*)d_ws + off_t);
        float2* svc      = (float2*)((char*)d_ws + off_svc);
        float2* sedge    = (float2*)((char*)d_ws + off_sedge);
        u16*    ebf      = (u16*)((char*)d_ws + off_ebf);
        int*    row_ptr  = (int*)((char*)d_ws + off_rowptr);
        int*    gcnt     = (int*)((char*)d_ws + off_gcnt);
        int*    bkt_ptr  = (int*)((char*)d_ws + off_ptr);
        int*    bkt_tail = (int*)((char*)d_ws + off_tails);

        // ---- bf16 source for stage 1 ----
        conv_e0<<<conv_blocks, 256, 0, stream>>>(user_emb, item_emb, ebf);

        // ---- bucket-sorted edge list + row_ptr (once, reused twice) ----
        hipMemsetAsync(gcnt, 0, (size_t)NBKT * sizeof(int), stream);
        bkt_hist<<<NBLK_L1, 256, 0, stream>>>(adj_rows, gcnt);
        scan_bkt<<<1, 256, 0, stream>>>(gcnt, bkt_ptr, bkt_tail);
        partition_l1<<<NBLK_L1, 256, 0, stream>>>(
            adj_vals, adj_rows, adj_cols, bkt_tail, svc);
        place_l2<<<NBKT, RB, 0, stream>>>(bkt_ptr, svc, sedge, row_ptr);
        // svc (inside t) is dead from here on

        // ---- stage 1: t = A @ e0 ; e1/e2/out ; e2 -> ebf (bf16) ----
        spmm_bf16<<<spmm_blocks, 256, 0, stream>>>(row_ptr, sedge, ebf, t);
        dense_stage<true><<<dense_blocks, 256, 0, stream>>>(
            t, W0, user_emb, item_emb, ebf, out);

        // ---- stage 2: t = A @ e2 ; out += 0.25*e3 ----
        spmm_bf16<<<spmm_blocks, 256, 0, stream>>>(row_ptr, sedge, ebf, t);
        dense_stage<false><<<dense_blocks, 256, 0, stream>>>(
            t, W1, nullptr, nullptr, nullptr, out);
    } else {
        // ---- fallback: round-1 atomic path ----
        float* t  = (float*)d_ws;
        float* e2 = (float*)((char*)d_ws + mat_bytes);

        hipMemsetAsync(t, 0, mat_bytes, stream);
        spmm_atomic<<<(N_EDGES + 3) / 4, 256, 0, stream>>>(
            adj_vals, adj_rows, adj_cols, user_emb, item_emb, t);
        dense_f32<true><<<dense_blocks, 256, 0, stream>>>(
            t, W0, user_emb, item_emb, e2, out);

        hipMemsetAsync(t, 0, mat_bytes, stream);
        spmm_atomic<<<(N_EDGES + 3) / 4, 256, 0, stream>>>(
            adj_vals, adj_rows, adj_cols, e2, nullptr, t);
        dense_f32<false><<<dense_blocks, 256, 0, stream>>>(
            t, W1, nullptr, nullptr, nullptr, out);
    }
}